// Round 2
// baseline (89021.313 us; speedup 1.0000x reference)
//
#include <hip/hip_runtime.h>
#include <hip/hip_bf16.h>
#include <math.h>

#define NB    2048
#define FIN   32
#define HH    512
#define G4    2048           // 4*H
#define BNE   64
#define OUTD  8
#define SEQL  128
#define LOOK  32
#define TOT   (SEQL + LOOK)
#define TB    8              // samples per workgroup
#define NTHR  512

__device__ __forceinline__ float sigf(float v) { return 1.0f / (1.0f + expf(-v)); }

// 8 FMAs: acc[s] += hs{s} * W   (hs0..hs7 are free variables at expansion site)
#define MAC8(ACC, W)                                   \
  {                                                    \
    ACC[0] = fmaf(hs0, (W), ACC[0]);                   \
    ACC[1] = fmaf(hs1, (W), ACC[1]);                   \
    ACC[2] = fmaf(hs2, (W), ACC[2]);                   \
    ACC[3] = fmaf(hs3, (W), ACC[3]);                   \
    ACC[4] = fmaf(hs4, (W), ACC[4]);                   \
    ACC[5] = fmaf(hs5, (W), ACC[5]);                   \
    ACC[6] = fmaf(hs6, (W), ACC[6]);                   \
    ACC[7] = fmaf(hs7, (W), ACC[7]);                   \
  }

__global__ __launch_bounds__(NTHR)
void fused_rnn(const float* __restrict__ x,
               const float* __restrict__ Wih0, const float* __restrict__ Whh0,
               const float* __restrict__ bih0, const float* __restrict__ bhh0,
               const float* __restrict__ Wih1, const float* __restrict__ Whh1,
               const float* __restrict__ bih1, const float* __restrict__ bhh1,
               const float* __restrict__ We,   const float* __restrict__ be,
               const float* __restrict__ Wd,   const float* __restrict__ bd,
               const float* __restrict__ Wf,   const float* __restrict__ bf,
               float* __restrict__ out)
{
  // states transposed [k][sample] so fixed-k access is a wave-uniform float4 broadcast
  __shared__ float sh0[HH][TB], sc0[HH][TB], sh1[HH][TB], sc1[HH][TB];  // 64 KB
  __shared__ float sq[2][TB][BNE];   // quantized bottleneck (as float -1/0/1), 4 KB
  __shared__ float sx[FIN][TB];      // staged x_t, transposed, 1 KB
  __shared__ float sout[TB][OUTD];   // last dense output (for AR feedback)

  const int t  = threadIdx.x;          // 0..511
  const int b0 = blockIdx.x * TB;      // first sample of this WG

  for (int i = t; i < HH * TB; i += NTHR) {
    (&sh0[0][0])[i] = 0.f; (&sc0[0][0])[i] = 0.f;
    (&sh1[0][0])[i] = 0.f; (&sc1[0][0])[i] = 0.f;
  }

  // per-thread gate biases: gate col = j*512 + t  (j: 0=i,1=f,2=g,3=o)
  float bias0[4], bias1[4];
#pragma unroll
  for (int j = 0; j < 4; j++) {
    bias0[j] = bih0[j * HH + t] + bhh0[j * HH + t];
    bias1[j] = bih1[j * HH + t] + bhh1[j * HH + t];
  }

  const double Athr = 0.5493061443340549;  // atanh(0.5): round(tanh(u)) threshold

  for (int step = 0; step < TOT; ++step) {
    __syncthreads();

    // ---------------- Phase A: encode both AEs (fp64 accumulation) ----------------
    {
      const int ae = t >> 8, s = (t >> 5) & 7, n = t & 31;
      const float* Sh = ae ? &sh1[0][0] : &sh0[0][0];
      const float* Sc = ae ? &sc1[0][0] : &sc0[0][0];
      double a0 = (double)be[n], a1 = (double)be[n + 32];
      const float* we0 = We + n;
#pragma unroll 4
      for (int k = 0; k < HH; k++) {
        double z = (double)Sh[k * TB + s];
        a0 = fma(z, (double)we0[k * BNE], a0);
        a1 = fma(z, (double)we0[k * BNE + 32], a1);
      }
      const float* we1 = We + (size_t)HH * BNE + n;
#pragma unroll 4
      for (int k = 0; k < HH; k++) {
        double z = (double)Sc[k * TB + s];
        a0 = fma(z, (double)we1[k * BNE], a0);
        a1 = fma(z, (double)we1[k * BNE + 32], a1);
      }
      sq[ae][s][n]      = (a0 > Athr) ? 1.f : ((a0 < -Athr) ? -1.f : 0.f);
      sq[ae][s][n + 32] = (a1 > Athr) ? 1.f : ((a1 < -Athr) ? -1.f : 0.f);
    }
    __syncthreads();

    // ---------------- Phase B: decode both AEs -> states; stage x_t ----------------
    {
      float ah0[TB], ac0[TB], ah1[TB], ac1[TB];
      const float bdh = bd[t], bdc = bd[HH + t];
#pragma unroll
      for (int s = 0; s < TB; s++) { ah0[s] = bdh; ac0[s] = bdc; ah1[s] = bdh; ac1[s] = bdc; }
      const float* wd0 = Wd + t;            // h-part col t
      const float* wd1 = Wd + HH + t;       // c-part col 512+t
#pragma unroll 2
      for (int j = 0; j < BNE; j++) {
        const float w0 = wd0[j * (2 * HH)];
        const float w1 = wd1[j * (2 * HH)];
#pragma unroll
        for (int s = 0; s < TB; s++) {
          float q0 = sq[0][s][j], q1 = sq[1][s][j];
          ah0[s] = fmaf(q0, w0, ah0[s]); ac0[s] = fmaf(q0, w1, ac0[s]);
          ah1[s] = fmaf(q1, w0, ah1[s]); ac1[s] = fmaf(q1, w1, ac1[s]);
        }
      }
#pragma unroll
      for (int s = 0; s < TB; s++) {
        sh0[t][s] = ah0[s]; sc0[t][s] = ac0[s];
        sh1[t][s] = ah1[s]; sc1[t][s] = ac1[s];
      }
      if (t < FIN * TB) {   // 256 threads stage x_t (with AR feedback)
        int s = t >> 5, f = t & 31;
        float xv;
        if (step >= SEQL && f < OUTD) xv = sout[s][f];
        else xv = x[((size_t)(b0 + s) * TOT + step) * FIN + f];
        sx[f][s] = xv;
      }
    }
    __syncthreads();

    // ---------------- Phase C: layer-0 LSTM ----------------
    {
      float accI[TB], accF[TB], accG[TB], accO[TB];
#pragma unroll
      for (int s = 0; s < TB; s++) { accI[s] = bias0[0]; accF[s] = bias0[1]; accG[s] = bias0[2]; accO[s] = bias0[3]; }

      { // x part, K=32
        const float* p0 = Wih0 + t;
        const float* p1 = Wih0 + t + 2 * HH;
#pragma unroll 4
        for (int k = 0; k < FIN; k++) {
          float w0 = p0[k * G4], w1 = p0[k * G4 + HH];
          float w2 = p1[k * G4], w3 = p1[k * G4 + HH];
          const float4 hA = *(const float4*)&sx[k][0];
          const float4 hB = *(const float4*)&sx[k][4];
          float hs0 = hA.x, hs1 = hA.y, hs2 = hA.z, hs3 = hA.w;
          float hs4 = hB.x, hs5 = hB.y, hs6 = hB.z, hs7 = hB.w;
          MAC8(accI, w0); MAC8(accF, w1); MAC8(accG, w2); MAC8(accO, w3);
        }
      }
      { // recurrent part, K=512
        const float* p0 = Whh0 + t;
        const float* p1 = Whh0 + t + 2 * HH;
#pragma unroll 4
        for (int k = 0; k < HH; k++) {
          float w0 = p0[k * G4], w1 = p0[k * G4 + HH];
          float w2 = p1[k * G4], w3 = p1[k * G4 + HH];
          const float4 hA = *(const float4*)&sh0[k][0];
          const float4 hB = *(const float4*)&sh0[k][4];
          float hs0 = hA.x, hs1 = hA.y, hs2 = hA.z, hs3 = hA.w;
          float hs4 = hB.x, hs5 = hB.y, hs6 = hB.z, hs7 = hB.w;
          MAC8(accI, w0); MAC8(accF, w1); MAC8(accG, w2); MAC8(accO, w3);
        }
      }
      float hn[TB], cn[TB];
      const float4 cA = *(const float4*)&sc0[t][0];
      const float4 cB = *(const float4*)&sc0[t][4];
      float cold[TB] = { cA.x, cA.y, cA.z, cA.w, cB.x, cB.y, cB.z, cB.w };
#pragma unroll
      for (int s = 0; s < TB; s++) {
        float ig = sigf(accI[s]), fg = sigf(accF[s]);
        float gg = tanhf(accG[s]), og = sigf(accO[s]);
        float c2 = fmaf(fg, cold[s], ig * gg);
        cn[s] = c2;
        hn[s] = og * tanhf(c2);
      }
      __syncthreads();  // all reads of sh0 complete before overwrite
      *(float4*)&sh0[t][0] = make_float4(hn[0], hn[1], hn[2], hn[3]);
      *(float4*)&sh0[t][4] = make_float4(hn[4], hn[5], hn[6], hn[7]);
      *(float4*)&sc0[t][0] = make_float4(cn[0], cn[1], cn[2], cn[3]);
      *(float4*)&sc0[t][4] = make_float4(cn[4], cn[5], cn[6], cn[7]);
    }
    __syncthreads();

    // ---------------- Phase D: layer-1 LSTM ----------------
    {
      float accI[TB], accF[TB], accG[TB], accO[TB];
#pragma unroll
      for (int s = 0; s < TB; s++) { accI[s] = bias1[0]; accF[s] = bias1[1]; accG[s] = bias1[2]; accO[s] = bias1[3]; }

      { // input = new h0, K=512
        const float* p0 = Wih1 + t;
        const float* p1 = Wih1 + t + 2 * HH;
#pragma unroll 4
        for (int k = 0; k < HH; k++) {
          float w0 = p0[k * G4], w1 = p0[k * G4 + HH];
          float w2 = p1[k * G4], w3 = p1[k * G4 + HH];
          const float4 hA = *(const float4*)&sh0[k][0];
          const float4 hB = *(const float4*)&sh0[k][4];
          float hs0 = hA.x, hs1 = hA.y, hs2 = hA.z, hs3 = hA.w;
          float hs4 = hB.x, hs5 = hB.y, hs6 = hB.z, hs7 = hB.w;
          MAC8(accI, w0); MAC8(accF, w1); MAC8(accG, w2); MAC8(accO, w3);
        }
      }
      { // recurrent = decoded h1, K=512
        const float* p0 = Whh1 + t;
        const float* p1 = Whh1 + t + 2 * HH;
#pragma unroll 4
        for (int k = 0; k < HH; k++) {
          float w0 = p0[k * G4], w1 = p0[k * G4 + HH];
          float w2 = p1[k * G4], w3 = p1[k * G4 + HH];
          const float4 hA = *(const float4*)&sh1[k][0];
          const float4 hB = *(const float4*)&sh1[k][4];
          float hs0 = hA.x, hs1 = hA.y, hs2 = hA.z, hs3 = hA.w;
          float hs4 = hB.x, hs5 = hB.y, hs6 = hB.z, hs7 = hB.w;
          MAC8(accI, w0); MAC8(accF, w1); MAC8(accG, w2); MAC8(accO, w3);
        }
      }
      float hn[TB], cn[TB];
      const float4 cA = *(const float4*)&sc1[t][0];
      const float4 cB = *(const float4*)&sc1[t][4];
      float cold[TB] = { cA.x, cA.y, cA.z, cA.w, cB.x, cB.y, cB.z, cB.w };
#pragma unroll
      for (int s = 0; s < TB; s++) {
        float ig = sigf(accI[s]), fg = sigf(accF[s]);
        float gg = tanhf(accG[s]), og = sigf(accO[s]);
        float c2 = fmaf(fg, cold[s], ig * gg);
        cn[s] = c2;
        hn[s] = og * tanhf(c2);
      }
      __syncthreads();  // all reads of sh1 complete before overwrite
      *(float4*)&sh1[t][0] = make_float4(hn[0], hn[1], hn[2], hn[3]);
      *(float4*)&sh1[t][4] = make_float4(hn[4], hn[5], hn[6], hn[7]);
      *(float4*)&sc1[t][0] = make_float4(cn[0], cn[1], cn[2], cn[3]);
      *(float4*)&sc1[t][4] = make_float4(cn[4], cn[5], cn[6], cn[7]);
    }

    // ---------------- Phase E: final dense (warm-up end + every AR step) ----------------
    if (step >= SEQL - 1) {
      __syncthreads();  // new sh1 visible
      if (t < TB * OUTD) {
        int s = t >> 3, o = t & 7;
        float a = bf[o];
#pragma unroll 4
        for (int k = 0; k < HH; k++) a = fmaf(sh1[k][s], Wf[k * OUTD + o], a);
        sout[s][o] = a;
        int slot = step - (SEQL - 1);                 // 0..32
        out[((size_t)(b0 + s) * (1 + LOOK) + slot) * OUTD + o] = a;
      }
    }
  }
}

extern "C" void kernel_launch(void* const* d_in, const int* in_sizes, int n_in,
                              void* d_out, int out_size, void* d_ws, size_t ws_size,
                              hipStream_t stream) {
  const float* x    = (const float*)d_in[0];
  const float* Wih0 = (const float*)d_in[1];
  const float* Whh0 = (const float*)d_in[2];
  const float* bih0 = (const float*)d_in[3];
  const float* bhh0 = (const float*)d_in[4];
  const float* Wih1 = (const float*)d_in[5];
  const float* Whh1 = (const float*)d_in[6];
  const float* bih1 = (const float*)d_in[7];
  const float* bhh1 = (const float*)d_in[8];
  const float* We   = (const float*)d_in[9];
  const float* be   = (const float*)d_in[10];
  const float* Wd   = (const float*)d_in[11];
  const float* bd   = (const float*)d_in[12];
  const float* Wf   = (const float*)d_in[13];
  const float* bf   = (const float*)d_in[14];

  fused_rnn<<<NB / TB, NTHR, 0, stream>>>(x, Wih0, Whh0, bih0, bhh0,
                                          Wih1, Whh1, bih1, bhh1,
                                          We, be, Wd, bd, Wf, bf,
                                          (float*)d_out);
}

// Round 3
// 81124.640 us; speedup vs baseline: 1.0973x; 1.0973x over previous
//
#include <hip/hip_runtime.h>
#include <hip/hip_bf16.h>
#include <math.h>

#define NB    2048
#define FIN   32
#define HH    512
#define G4    2048           // 4*H
#define BNE   64
#define OUTD  8
#define SEQL  128
#define LOOK  32
#define TOT   (SEQL + LOOK)
#define TB    8              // samples per workgroup
#define NTHR  1024

__device__ __forceinline__ float sigf(float v) { return 1.0f / (1.0f + expf(-v)); }

// acc[s] (float2) += state_s * w (float2)
#define MAC2(S, HS)                                    \
  {                                                    \
    a[S].x = fmaf(w.x, (HS), a[S].x);                  \
    a[S].y = fmaf(w.y, (HS), a[S].y);                  \
  }
#define MAC2x8()                                       \
  {                                                    \
    MAC2(0, hA.x); MAC2(1, hA.y); MAC2(2, hA.z); MAC2(3, hA.w); \
    MAC2(4, hB.x); MAC2(5, hB.y); MAC2(6, hB.z); MAC2(7, hB.w); \
  }

__global__ __launch_bounds__(NTHR)
void fused_rnn(const float* __restrict__ x,
               const float* __restrict__ Wih0, const float* __restrict__ Whh0,
               const float* __restrict__ bih0, const float* __restrict__ bhh0,
               const float* __restrict__ Wih1, const float* __restrict__ Whh1,
               const float* __restrict__ bih1, const float* __restrict__ bhh1,
               const float* __restrict__ We,   const float* __restrict__ be,
               const float* __restrict__ Wd,   const float* __restrict__ bd,
               const float* __restrict__ Wf,   const float* __restrict__ bf,
               float* __restrict__ out)
{
  // states transposed [k][sample]: fixed-k access = wave-uniform float4 broadcast
  __shared__ float sh0[HH][TB], sc0[HH][TB], sh1[HH][TB], sc1[HH][TB];  // 64 KB
  __shared__ float sg[TB][G4];       // gate pre-activations [sample][col], 64 KB
  __shared__ float sq[2][BNE][TB];   // trits [ae][j][sample], 4 KB
  __shared__ float sx[FIN][TB];      // staged x_t, transposed, 1 KB
  __shared__ float sout[TB][OUTD];   // last dense output (AR feedback)

  const int t  = threadIdx.x;          // 0..1023
  const int b0 = blockIdx.x * TB;      // first sample of this WG

  for (int i = t; i < HH * TB; i += NTHR) {
    (&sh0[0][0])[i] = 0.f; (&sc0[0][0])[i] = 0.f;
    (&sh1[0][0])[i] = 0.f; (&sc1[0][0])[i] = 0.f;
  }

  // this thread owns gate cols (2t, 2t+1); bias = bih+bhh for those cols
  const float2 bb0 = make_float2(bih0[2*t]   + bhh0[2*t],
                                 bih0[2*t+1] + bhh0[2*t+1]);
  const float2 bb1 = make_float2(bih1[2*t]   + bhh1[2*t],
                                 bih1[2*t+1] + bhh1[2*t+1]);

  const double Athr = 0.5493061443340549;  // atanh(0.5): round(tanh(u)) threshold

  for (int step = 0; step < TOT; ++step) {
    __syncthreads();

    // ---------------- Phase A: encode both AEs (fp64, 1 bottleneck unit/thread) ----
    {
      const int ae = t >> 9, s = (t >> 6) & 7, n = t & 63;
      const float* Sh = ae ? &sh1[0][0] : &sh0[0][0];
      const float* Sc = ae ? &sc1[0][0] : &sc0[0][0];
      double a0 = (double)be[n];
      const float* we0 = We + n;
#pragma unroll 4
      for (int k = 0; k < HH; k++)
        a0 = fma((double)Sh[k * TB + s], (double)we0[(size_t)k * BNE], a0);
      const float* we1 = We + (size_t)HH * BNE + n;
#pragma unroll 4
      for (int k = 0; k < HH; k++)
        a0 = fma((double)Sc[k * TB + s], (double)we1[(size_t)k * BNE], a0);
      sq[ae][n][s] = (a0 > Athr) ? 1.f : ((a0 < -Athr) ? -1.f : 0.f);
    }
    __syncthreads();

    // ---------------- Phase B: decode both AEs (1 col/thread) -> states; stage x_t --
    {
      float aq0[TB], aq1[TB];
      const float bdv = bd[t];
#pragma unroll
      for (int s = 0; s < TB; s++) { aq0[s] = bdv; aq1[s] = bdv; }
      const float* wd = Wd + t;          // col t, row stride 1024
#pragma unroll 2
      for (int j = 0; j < BNE; j++) {
        const float w = wd[(size_t)j * (2 * HH)];
        const float4 qA0 = *(const float4*)&sq[0][j][0];
        const float4 qB0 = *(const float4*)&sq[0][j][4];
        const float4 qA1 = *(const float4*)&sq[1][j][0];
        const float4 qB1 = *(const float4*)&sq[1][j][4];
        aq0[0] = fmaf(qA0.x, w, aq0[0]); aq0[1] = fmaf(qA0.y, w, aq0[1]);
        aq0[2] = fmaf(qA0.z, w, aq0[2]); aq0[3] = fmaf(qA0.w, w, aq0[3]);
        aq0[4] = fmaf(qB0.x, w, aq0[4]); aq0[5] = fmaf(qB0.y, w, aq0[5]);
        aq0[6] = fmaf(qB0.z, w, aq0[6]); aq0[7] = fmaf(qB0.w, w, aq0[7]);
        aq1[0] = fmaf(qA1.x, w, aq1[0]); aq1[1] = fmaf(qA1.y, w, aq1[1]);
        aq1[2] = fmaf(qA1.z, w, aq1[2]); aq1[3] = fmaf(qA1.w, w, aq1[3]);
        aq1[4] = fmaf(qB1.x, w, aq1[4]); aq1[5] = fmaf(qB1.y, w, aq1[5]);
        aq1[6] = fmaf(qB1.z, w, aq1[6]); aq1[7] = fmaf(qB1.w, w, aq1[7]);
      }
      if (t < HH) {
#pragma unroll
        for (int s = 0; s < TB; s++) { sh0[t][s] = aq0[s]; sh1[t][s] = aq1[s]; }
      } else {
        const int c = t - HH;
#pragma unroll
        for (int s = 0; s < TB; s++) { sc0[c][s] = aq0[s]; sc1[c][s] = aq1[s]; }
      }
      if (t < FIN * TB) {   // 256 threads stage x_t (with AR feedback)
        int s = t >> 5, f = t & 31;
        float xv;
        if (step >= SEQL && f < OUTD) xv = sout[s][f];
        else xv = x[((size_t)(b0 + s) * TOT + step) * FIN + f];
        sx[f][s] = xv;
      }
    }
    __syncthreads();

    // ---------------- Phase C: layer-0 matmul (col pair/thread) ----------------
    {
      float2 a[TB];
#pragma unroll
      for (int s = 0; s < TB; s++) a[s] = bb0;
      const float2* wx = (const float2*)Wih0 + t;
#pragma unroll 4
      for (int k = 0; k < FIN; k++) {
        const float2 w  = wx[(size_t)k * (G4 / 2)];
        const float4 hA = *(const float4*)&sx[k][0];
        const float4 hB = *(const float4*)&sx[k][4];
        MAC2x8();
      }
      const float2* wh = (const float2*)Whh0 + t;
#pragma unroll 8
      for (int k = 0; k < HH; k++) {
        const float2 w  = wh[(size_t)k * (G4 / 2)];
        const float4 hA = *(const float4*)&sh0[k][0];
        const float4 hB = *(const float4*)&sh0[k][4];
        MAC2x8();
      }
#pragma unroll
      for (int s = 0; s < TB; s++) *(float2*)&sg[s][2 * t] = a[s];
    }
    __syncthreads();
    // layer-0 elementwise: unit h = t&511, 4 samples per thread
    {
      const int h  = t & (HH - 1);
      const int sb = (t >> 9) * 4;
#pragma unroll
      for (int s2 = 0; s2 < 4; s2++) {
        const int s = sb + s2;
        const float ig = sigf(sg[s][h]);
        const float fg = sigf(sg[s][HH + h]);
        const float gt = tanhf(sg[s][2 * HH + h]);
        const float og = sigf(sg[s][3 * HH + h]);
        const float c2 = fmaf(fg, sc0[h][s], ig * gt);
        sc0[h][s] = c2;
        sh0[h][s] = og * tanhf(c2);
      }
    }
    __syncthreads();

    // ---------------- Phase D: layer-1 matmul ----------------
    {
      float2 a[TB];
#pragma unroll
      for (int s = 0; s < TB; s++) a[s] = bb1;
      const float2* wx = (const float2*)Wih1 + t;
#pragma unroll 8
      for (int k = 0; k < HH; k++) {
        const float2 w  = wx[(size_t)k * (G4 / 2)];
        const float4 hA = *(const float4*)&sh0[k][0];   // new h0
        const float4 hB = *(const float4*)&sh0[k][4];
        MAC2x8();
      }
      const float2* wh = (const float2*)Whh1 + t;
#pragma unroll 8
      for (int k = 0; k < HH; k++) {
        const float2 w  = wh[(size_t)k * (G4 / 2)];
        const float4 hA = *(const float4*)&sh1[k][0];   // decoded h1
        const float4 hB = *(const float4*)&sh1[k][4];
        MAC2x8();
      }
#pragma unroll
      for (int s = 0; s < TB; s++) *(float2*)&sg[s][2 * t] = a[s];
    }
    __syncthreads();
    // layer-1 elementwise
    {
      const int h  = t & (HH - 1);
      const int sb = (t >> 9) * 4;
#pragma unroll
      for (int s2 = 0; s2 < 4; s2++) {
        const int s = sb + s2;
        const float ig = sigf(sg[s][h]);
        const float fg = sigf(sg[s][HH + h]);
        const float gt = tanhf(sg[s][2 * HH + h]);
        const float og = sigf(sg[s][3 * HH + h]);
        const float c2 = fmaf(fg, sc1[h][s], ig * gt);
        sc1[h][s] = c2;
        sh1[h][s] = og * tanhf(c2);
      }
    }

    // ---------------- Phase E: final dense (warm-up end + every AR step) ----------
    if (step >= SEQL - 1) {
      __syncthreads();  // new sh1 visible
      if (t < TB * OUTD) {
        int s = t >> 3, o = t & 7;
        float a = bf[o];
#pragma unroll 4
        for (int k = 0; k < HH; k++) a = fmaf(sh1[k][s], Wf[k * OUTD + o], a);
        sout[s][o] = a;
        int slot = step - (SEQL - 1);                 // 0..32
        out[((size_t)(b0 + s) * (1 + LOOK) + slot) * OUTD + o] = a;
      }
    }
  }
}

extern "C" void kernel_launch(void* const* d_in, const int* in_sizes, int n_in,
                              void* d_out, int out_size, void* d_ws, size_t ws_size,
                              hipStream_t stream) {
  const float* x    = (const float*)d_in[0];
  const float* Wih0 = (const float*)d_in[1];
  const float* Whh0 = (const float*)d_in[2];
  const float* bih0 = (const float*)d_in[3];
  const float* bhh0 = (const float*)d_in[4];
  const float* Wih1 = (const float*)d_in[5];
  const float* Whh1 = (const float*)d_in[6];
  const float* bih1 = (const float*)d_in[7];
  const float* bhh1 = (const float*)d_in[8];
  const float* We   = (const float*)d_in[9];
  const float* be   = (const float*)d_in[10];
  const float* Wd   = (const float*)d_in[11];
  const float* bd   = (const float*)d_in[12];
  const float* Wf   = (const float*)d_in[13];
  const float* bf   = (const float*)d_in[14];

  fused_rnn<<<NB / TB, NTHR, 0, stream>>>(x, Wih0, Whh0, bih0, bhh0,
                                          Wih1, Whh1, bih1, bhh1,
                                          We, be, Wd, bd, Wf, bf,
                                          (float*)d_out);
}